// Round 6
// baseline (120.908 us; speedup 1.0000x reference)
//
#include <hip/hip_runtime.h>
#include <math.h>

// Problem constants
constexpr int NB  = 16;    // batch
constexpr int NH  = 50;    // history
constexpr int NS  = 512;   // signals
constexpr int ND  = 256;   // dim
constexpr int NK  = 8;     // top-k
constexpr int SM1 = NS - 1;             // 511 candidate positions
constexpr int ROWS = NH * (NK + 1) - 1; // 449 output rows per batch
constexpr int HB  = 5;     // h-values per block in query kernel
constexpr int CHUNKS = 4;  // score chunks per (b,h)

// DPP-based add of a lane-permuted value (pure VALU, no LDS pipe).
// CTRL: 0xB1 = quad_perm swap-1, 0x4E = quad_perm swap-2,
//       0x141 = row_half_mirror, 0x140 = row_mirror.
template<int CTRL>
__device__ __forceinline__ float dpp_add(float v) {
    const int p = __builtin_amdgcn_update_dpp(0, __float_as_int(v), CTRL, 0xF, 0xF, true);
    return v + __int_as_float(p);
}

__device__ __forceinline__ float dpp_reduce16(float v) {
    v = dpp_add<0xB1>(v);
    v = dpp_add<0x4E>(v);
    v = dpp_add<0x141>(v);
    v = dpp_add<0x140>(v);
    return v;
}

// full 64-lane sum; result in all lanes
__device__ __forceinline__ float wave_reduce64(float v) {
    v = dpp_reduce16(v);
    v += __shfl_xor(v, 16, 64);
    v += __shfl_xor(v, 32, 64);
    return v;
}

// ---------------------------------------------------------------------------
// Kernel 1 (unchanged from R5): coalesced-W query GEMV.
// ---------------------------------------------------------------------------
__global__ __launch_bounds__(256) void query_kernel(
    const float* __restrict__ user,      // (NB, 1, ND)
    const float* __restrict__ news_repr, // (NB, NH, ND)
    const float* __restrict__ W,         // (ND, 2*ND) row-major
    const float* __restrict__ bal,       // (ND)
    float* __restrict__ qn)              // (NB*NH, ND)
{
    __shared__ float us[ND];
    __shared__ float nr[HB][ND];
    __shared__ float qv_s[HB][ND];
    __shared__ float red[4];

    const int blk = blockIdx.x;
    const int b   = blk / (NH / HB);
    const int h0  = (blk % (NH / HB)) * HB;
    const int tid = threadIdx.x;
    const int ql  = tid & 15;   // lane within quarter
    const int q   = tid >> 4;   // quarter id 0..15

    us[tid] = user[b * ND + tid];
    #pragma unroll
    for (int i = 0; i < HB; ++i)
        nr[i][tid] = news_repr[((size_t)(b * NH + h0 + i)) * ND + tid];
    __syncthreads();

    for (int p = 0; p < 16; ++p) {
        const int d = p * 16 + q;
        const float* wrow = W + (size_t)d * (2 * ND);
        float pu = 0.f;
        float pa[HB];
        #pragma unroll
        for (int j = 0; j < HB; ++j) pa[j] = 0.f;

        #pragma unroll
        for (int i = 0; i < 4; ++i) {        // user half: e = ql*4 + 64*i
            const int e = ql * 4 + 64 * i;
            const float4 wv = *(const float4*)(wrow + e);
            const float4 xv = *(const float4*)(us + e);
            pu += wv.x * xv.x + wv.y * xv.y + wv.z * xv.z + wv.w * xv.w;
        }
        #pragma unroll
        for (int i = 0; i < 4; ++i) {        // repr half
            const int e = ql * 4 + 64 * i;
            const float4 wv = *(const float4*)(wrow + ND + e);
            #pragma unroll
            for (int j = 0; j < HB; ++j) {
                const float4 xv = *(const float4*)(&nr[j][e]);
                pa[j] += wv.x * xv.x + wv.y * xv.y + wv.z * xv.z + wv.w * xv.w;
            }
        }

        pu = dpp_reduce16(pu);
        #pragma unroll
        for (int j = 0; j < HB; ++j) pa[j] = dpp_reduce16(pa[j]);

        if (ql == 0) {
            const float base = bal[d] + pu;
            #pragma unroll
            for (int j = 0; j < HB; ++j) qv_s[j][d] = base + pa[j];
        }
    }
    __syncthreads();

    const int lane = tid & 63, wv_ = tid >> 6;
    for (int j = 0; j < HB; ++j) {
        const float v = qv_s[j][tid];
        float sq = v * v;
        #pragma unroll
        for (int m = 1; m < 64; m <<= 1) sq += __shfl_xor(sq, m, 64);
        if (lane == 0) red[wv_] = sq;
        __syncthreads();
        const float tot = red[0] + red[1] + red[2] + red[3];
        __syncthreads();
        qn[((size_t)(b * NH + h0 + j)) * ND + tid] = v / fmaxf(sqrtf(tot), 1e-12f);
    }
}

// ---------------------------------------------------------------------------
// Kernel 2 (REWRITTEN): wave-per-row scores.
// grid = NB*NH*CHUNKS blocks, 256 threads = 4 waves.
// Wave w owns rows [chunk*128 + w*32, +32): a contiguous 32 KB run.
// Per row: ONE contiguous 1 KB load per wave instruction (lane l -> floats
// [4l,4l+4)), rows in groups of 4 (independent loads), 64-lane DPP+shfl
// reduce, coalesced 16B store of 4 scores by lanes 0-3.
// ---------------------------------------------------------------------------
__global__ __launch_bounds__(256) void score_kernel(
    const float* __restrict__ sel,  // (NB,NH,NS,ND)
    const float* __restrict__ qn,   // (NB*NH, ND)
    float* __restrict__ scw)        // (NB*NH, NS)
{
    const int blk   = blockIdx.x;
    const int bh    = blk >> 2;     // / CHUNKS
    const int chunk = blk & (CHUNKS - 1);
    const int wv    = threadIdx.x >> 6;
    const int lane  = threadIdx.x & 63;

    // lane's 4 query dims [lane*4, +4) — one 1 KB wave load, L1-shared
    const float4 q4 = *(const float4*)(qn + (size_t)bh * ND + lane * 4);

    const float* base_bh = sel + (size_t)bh * NS * ND;
    const int r0 = chunk * 128 + wv * 32;   // first j of this wave's run

    #pragma unroll 2
    for (int g = 0; g < 8; ++g) {
        const int j = r0 + g * 4;           // rows j .. j+3
        float sc[4];
        float4 v[4];
        #pragma unroll
        for (int r = 0; r < 4; ++r) {
            const int jj = j + r;
            const int s = (jj < SM1) ? (jj + 1) : SM1;   // j=511 -> safe dummy row
            v[r] = *(const float4*)(base_bh + (size_t)s * ND + lane * 4);
        }
        #pragma unroll
        for (int r = 0; r < 4; ++r) {
            float dot = v[r].x * q4.x + v[r].y * q4.y + v[r].z * q4.z + v[r].w * q4.w;
            float nrm = v[r].x * v[r].x + v[r].y * v[r].y + v[r].z * v[r].z + v[r].w * v[r].w;
            dot = wave_reduce64(dot);
            nrm = wave_reduce64(nrm);
            sc[r] = dot / fmaxf(sqrtf(nrm), 1e-12f);
        }
        // lanes 0-3 write the 4 scores as one coalesced 16B segment
        const float mysc = (lane == 0) ? sc[0] : (lane == 1) ? sc[1]
                         : (lane == 2) ? sc[2] : sc[3];
        if (lane < 4 && j + lane < SM1)
            scw[(size_t)bh * NS + j + lane] = mysc;
    }
}

// ---------------------------------------------------------------------------
// Kernel 3 (unchanged from R4): one wave per (b,h). grid = NB*NH, 64 threads.
// ---------------------------------------------------------------------------
__global__ __launch_bounds__(64) void topk_out_kernel(
    const float* __restrict__ emb,     // (NB,NH,NS,ND)
    const int*   __restrict__ attn,    // (NB,NH,NS)
    const int*   __restrict__ refined, // (NB,NH,NS)
    const float* __restrict__ scw,     // (NB*NH, NS) raw scores
    const float* __restrict__ sep,     // (ND)
    const float* __restrict__ orde,    // (NH, 1, ND)
    float* __restrict__ out_terms,     // (NB, ROWS, ND)
    float* __restrict__ out_mask,      // (NB, ROWS)
    float* __restrict__ out_kid)       // (NB, NH, NK) as float
{
    const int bh   = blockIdx.x;
    const int b    = bh / NH, h = bh % NH;
    const int lane = threadIdx.x;

    float v[8];
    {
        const float4 a = *(const float4*)(scw + (size_t)bh * NS + lane * 8);
        const float4 c = *(const float4*)(scw + (size_t)bh * NS + lane * 8 + 4);
        v[0] = a.x; v[1] = a.y; v[2] = a.z; v[3] = a.w;
        v[4] = c.x; v[5] = c.y; v[6] = c.z; v[7] = c.w;
    }
    #pragma unroll
    for (int t = 0; t < 8; ++t) {
        const int j = lane * 8 + t;
        if (j >= SM1)
            v[t] = -INFINITY;
        else if (j >= NK && refined[(size_t)bh * NS + j + 1] == 0)
            v[t] = -INFINITY;
    }

    float topv[NK];
    int   topi[NK];
    int   myi = 0;
    #pragma unroll
    for (int k = 0; k < NK; ++k) {
        float bv = -INFINITY; int bi = 0x7fffffff;
        #pragma unroll
        for (int t = 0; t < 8; ++t)
            if (v[t] > bv) { bv = v[t]; bi = lane * 8 + t; }
        #pragma unroll
        for (int m = 1; m < 64; m <<= 1) {
            const float ov = __shfl_xor(bv, m, 64);
            const int   oi = __shfl_xor(bi, m, 64);
            if (ov > bv || (ov == bv && oi < bi)) { bv = ov; bi = oi; }
        }
        topv[k] = bv; topi[k] = bi;
        if (lane == k) myi = bi;
        #pragma unroll
        for (int t = 0; t < 8; ++t)
            if (lane * 8 + t == bi) v[t] = -INFINITY;
    }

    float wk[NK], ssum = 0.f;
    #pragma unroll
    for (int k = 0; k < NK; ++k) { wk[k] = expf(topv[k] - topv[0]); ssum += wk[k]; }
    const float inv = 1.f / ssum;

    const int d4 = lane * 4;
    const float4 ord4 = *(const float4*)(orde + (size_t)h * ND + d4);
    float* obase = out_terms + ((size_t)b * ROWS + h * (NK + 1)) * ND;
    #pragma unroll
    for (int k = 0; k < NK; ++k) {
        const int s = topi[k] + 1;
        const float4 e = *(const float4*)(emb + ((size_t)bh * NS + s) * ND + d4);
        const float w = wk[k] * inv;
        float4 o;
        o.x = e.x * w + ord4.x;
        o.y = e.y * w + ord4.y;
        o.z = e.z * w + ord4.z;
        o.w = e.w * w + ord4.w;
        *(float4*)(obase + k * ND + d4) = o;
    }
    const bool has_sep = h < NH - 1;
    if (has_sep)
        *(float4*)(obase + NK * ND + d4) = *(const float4*)(sep + d4);

    if (lane < NK) {
        out_mask[(size_t)b * ROWS + h * (NK + 1) + lane] =
            (float)attn[(size_t)bh * NS + myi + 1];
        out_kid[(size_t)bh * NK + lane] = (float)myi;
    }
    if (lane == NK && has_sep)
        out_mask[(size_t)b * ROWS + h * (NK + 1) + NK] = 1.0f;
}

// ---------------------------------------------------------------------------
extern "C" void kernel_launch(void* const* d_in, const int* in_sizes, int n_in,
                              void* d_out, int out_size, void* d_ws, size_t ws_size,
                              hipStream_t stream) {
    const float* sel   = (const float*)d_in[0];
    const float* emb   = (const float*)d_in[1];
    const float* user  = (const float*)d_in[2];
    const float* nrp   = (const float*)d_in[3];
    const int*   attn  = (const int*)d_in[4];
    const int*   refin = (const int*)d_in[5];
    const float* W     = (const float*)d_in[6];
    const float* bal   = (const float*)d_in[7];
    const float* sep   = (const float*)d_in[8];
    const float* orde  = (const float*)d_in[9];

    float* qn  = (float*)d_ws;                       // NB*NH*ND floats (800 KB)
    float* scw = qn + (size_t)NB * NH * ND;          // NB*NH*NS floats (1.6 MB)

    float* out_terms = (float*)d_out;
    float* out_mask  = out_terms + (size_t)NB * ROWS * ND;
    float* out_kid   = out_mask + (size_t)NB * ROWS;

    query_kernel<<<NB * (NH / HB), 256, 0, stream>>>(user, nrp, W, bal, qn);
    score_kernel<<<NB * NH * CHUNKS, 256, 0, stream>>>(sel, qn, scw);
    topk_out_kernel<<<NB * NH, 64, 0, stream>>>(emb, attn, refin, scw, sep, orde,
                                                out_terms, out_mask, out_kid);
}

// Round 7
// 93.349 us; speedup vs baseline: 1.2952x; 1.2952x over previous
//
#include <hip/hip_runtime.h>
#include <math.h>

// Problem constants
constexpr int NB  = 16;    // batch
constexpr int NH  = 50;    // history
constexpr int NS  = 512;   // signals
constexpr int ND  = 256;   // dim
constexpr int NK  = 8;     // top-k
constexpr int SM1 = NS - 1;             // 511 candidate positions
constexpr int ROWS = NH * (NK + 1) - 1; // 449 output rows per batch
constexpr int HB  = 5;     // h-values per block in query kernel
constexpr int CHUNKS = 4;  // score chunks per (b,h)
constexpr int RPC = 128;   // rows per chunk (last chunk covers 127 valid)

// DPP-based add of a lane-permuted value (pure VALU, no LDS pipe).
template<int CTRL>
__device__ __forceinline__ float dpp_add(float v) {
    const int p = __builtin_amdgcn_update_dpp(0, __float_as_int(v), CTRL, 0xF, 0xF, true);
    return v + __int_as_float(p);
}

__device__ __forceinline__ float dpp_reduce16(float v) {
    v = dpp_add<0xB1>(v);
    v = dpp_add<0x4E>(v);
    v = dpp_add<0x141>(v);
    v = dpp_add<0x140>(v);
    return v;
}

// Non-temporal float4 load: no-allocate streaming read (emits nt-flagged
// global_load_dwordx4). sel is read exactly once -> cache-bypass is free.
__device__ __forceinline__ float4 ntload4(const float* p) {
    typedef float f4v __attribute__((ext_vector_type(4)));
    const f4v v = __builtin_nontemporal_load((const f4v*)p);
    float4 r; r.x = v.x; r.y = v.y; r.z = v.z; r.w = v.w;
    return r;
}

// ---------------------------------------------------------------------------
// Kernel 1 (unchanged from R5): coalesced-W query GEMV.
// ---------------------------------------------------------------------------
__global__ __launch_bounds__(256) void query_kernel(
    const float* __restrict__ user,      // (NB, 1, ND)
    const float* __restrict__ news_repr, // (NB, NH, ND)
    const float* __restrict__ W,         // (ND, 2*ND) row-major
    const float* __restrict__ bal,       // (ND)
    float* __restrict__ qn)              // (NB*NH, ND)
{
    __shared__ float us[ND];
    __shared__ float nr[HB][ND];
    __shared__ float qv_s[HB][ND];
    __shared__ float red[4];

    const int blk = blockIdx.x;
    const int b   = blk / (NH / HB);
    const int h0  = (blk % (NH / HB)) * HB;
    const int tid = threadIdx.x;
    const int ql  = tid & 15;   // lane within quarter
    const int q   = tid >> 4;   // quarter id 0..15

    us[tid] = user[b * ND + tid];
    #pragma unroll
    for (int i = 0; i < HB; ++i)
        nr[i][tid] = news_repr[((size_t)(b * NH + h0 + i)) * ND + tid];
    __syncthreads();

    for (int p = 0; p < 16; ++p) {
        const int d = p * 16 + q;
        const float* wrow = W + (size_t)d * (2 * ND);
        float pu = 0.f;
        float pa[HB];
        #pragma unroll
        for (int j = 0; j < HB; ++j) pa[j] = 0.f;

        #pragma unroll
        for (int i = 0; i < 4; ++i) {        // user half: e = ql*4 + 64*i
            const int e = ql * 4 + 64 * i;
            const float4 wv = *(const float4*)(wrow + e);
            const float4 xv = *(const float4*)(us + e);
            pu += wv.x * xv.x + wv.y * xv.y + wv.z * xv.z + wv.w * xv.w;
        }
        #pragma unroll
        for (int i = 0; i < 4; ++i) {        // repr half
            const int e = ql * 4 + 64 * i;
            const float4 wv = *(const float4*)(wrow + ND + e);
            #pragma unroll
            for (int j = 0; j < HB; ++j) {
                const float4 xv = *(const float4*)(&nr[j][e]);
                pa[j] += wv.x * xv.x + wv.y * xv.y + wv.z * xv.z + wv.w * xv.w;
            }
        }

        pu = dpp_reduce16(pu);
        #pragma unroll
        for (int j = 0; j < HB; ++j) pa[j] = dpp_reduce16(pa[j]);

        if (ql == 0) {
            const float base = bal[d] + pu;
            #pragma unroll
            for (int j = 0; j < HB; ++j) qv_s[j][d] = base + pa[j];
        }
    }
    __syncthreads();

    const int lane = tid & 63, wv_ = tid >> 6;
    for (int j = 0; j < HB; ++j) {
        const float v = qv_s[j][tid];
        float sq = v * v;
        #pragma unroll
        for (int m = 1; m < 64; m <<= 1) sq += __shfl_xor(sq, m, 64);
        if (lane == 0) red[wv_] = sq;
        __syncthreads();
        const float tot = red[0] + red[1] + red[2] + red[3];
        __syncthreads();
        qn[((size_t)(b * NH + h0 + j)) * ND + tid] = v / fmaxf(sqrtf(tot), 1e-12f);
    }
}

// ---------------------------------------------------------------------------
// Kernel 2: scores (R5 structure; sel loads now NON-TEMPORAL).
// grid = NB*NH*CHUNKS blocks, 256 threads; quarter-wave per row.
// ---------------------------------------------------------------------------
__global__ __launch_bounds__(256) void score_kernel(
    const float* __restrict__ sel,  // (NB,NH,NS,ND)
    const float* __restrict__ qn,   // (NB*NH, ND)
    float* __restrict__ scw)        // (NB*NH, NS)
{
    const int blk   = blockIdx.x;
    const int bh    = blk >> 2;     // / CHUNKS
    const int chunk = blk & (CHUNKS - 1);
    const int j0    = chunk * RPC;
    const int tid   = threadIdx.x;
    const int ql    = tid & 15;     // lane within quarter
    const int q     = tid >> 4;     // quarter id 0..15

    float4 qf[4];
    #pragma unroll
    for (int i = 0; i < 4; ++i)
        qf[i] = *(const float4*)(qn + (size_t)bh * ND + i * 64 + ql * 4);

    const float* base_bh = sel + (size_t)bh * NS * ND;

    #pragma unroll 2
    for (int it = 0; it < 8; ++it) {
        const int j = j0 + q + it * 16;
        const bool valid = (j < SM1);
        const int s = valid ? (j + 1) : SM1;   // safe in-bounds row for the dummy
        const float* row = base_bh + (size_t)s * ND;
        float dot = 0.f, nrm = 0.f;
        #pragma unroll
        for (int i = 0; i < 4; ++i) {
            const float4 v = ntload4(row + i * 64 + ql * 4);
            dot += v.x * qf[i].x + v.y * qf[i].y + v.z * qf[i].z + v.w * qf[i].w;
            nrm += v.x * v.x + v.y * v.y + v.z * v.z + v.w * v.w;
        }
        dot = dpp_reduce16(dot);
        nrm = dpp_reduce16(nrm);

        if (valid && ql == 0)
            scw[(size_t)bh * NS + j] = dot / fmaxf(sqrtf(nrm), 1e-12f);
    }
}

// ---------------------------------------------------------------------------
// Kernel 3 (unchanged from R4): one wave per (b,h). grid = NB*NH, 64 threads.
// ---------------------------------------------------------------------------
__global__ __launch_bounds__(64) void topk_out_kernel(
    const float* __restrict__ emb,     // (NB,NH,NS,ND)
    const int*   __restrict__ attn,    // (NB,NH,NS)
    const int*   __restrict__ refined, // (NB,NH,NS)
    const float* __restrict__ scw,     // (NB*NH, NS) raw scores
    const float* __restrict__ sep,     // (ND)
    const float* __restrict__ orde,    // (NH, 1, ND)
    float* __restrict__ out_terms,     // (NB, ROWS, ND)
    float* __restrict__ out_mask,      // (NB, ROWS)
    float* __restrict__ out_kid)       // (NB, NH, NK) as float
{
    const int bh   = blockIdx.x;
    const int b    = bh / NH, h = bh % NH;
    const int lane = threadIdx.x;

    float v[8];
    {
        const float4 a = *(const float4*)(scw + (size_t)bh * NS + lane * 8);
        const float4 c = *(const float4*)(scw + (size_t)bh * NS + lane * 8 + 4);
        v[0] = a.x; v[1] = a.y; v[2] = a.z; v[3] = a.w;
        v[4] = c.x; v[5] = c.y; v[6] = c.z; v[7] = c.w;
    }
    #pragma unroll
    for (int t = 0; t < 8; ++t) {
        const int j = lane * 8 + t;
        if (j >= SM1)
            v[t] = -INFINITY;
        else if (j >= NK && refined[(size_t)bh * NS + j + 1] == 0)
            v[t] = -INFINITY;
    }

    float topv[NK];
    int   topi[NK];
    int   myi = 0;
    #pragma unroll
    for (int k = 0; k < NK; ++k) {
        float bv = -INFINITY; int bi = 0x7fffffff;
        #pragma unroll
        for (int t = 0; t < 8; ++t)
            if (v[t] > bv) { bv = v[t]; bi = lane * 8 + t; }
        #pragma unroll
        for (int m = 1; m < 64; m <<= 1) {
            const float ov = __shfl_xor(bv, m, 64);
            const int   oi = __shfl_xor(bi, m, 64);
            if (ov > bv || (ov == bv && oi < bi)) { bv = ov; bi = oi; }
        }
        topv[k] = bv; topi[k] = bi;
        if (lane == k) myi = bi;
        #pragma unroll
        for (int t = 0; t < 8; ++t)
            if (lane * 8 + t == bi) v[t] = -INFINITY;
    }

    float wk[NK], ssum = 0.f;
    #pragma unroll
    for (int k = 0; k < NK; ++k) { wk[k] = expf(topv[k] - topv[0]); ssum += wk[k]; }
    const float inv = 1.f / ssum;

    const int d4 = lane * 4;
    const float4 ord4 = *(const float4*)(orde + (size_t)h * ND + d4);
    float* obase = out_terms + ((size_t)b * ROWS + h * (NK + 1)) * ND;
    #pragma unroll
    for (int k = 0; k < NK; ++k) {
        const int s = topi[k] + 1;
        const float4 e = *(const float4*)(emb + ((size_t)bh * NS + s) * ND + d4);
        const float w = wk[k] * inv;
        float4 o;
        o.x = e.x * w + ord4.x;
        o.y = e.y * w + ord4.y;
        o.z = e.z * w + ord4.z;
        o.w = e.w * w + ord4.w;
        *(float4*)(obase + k * ND + d4) = o;
    }
    const bool has_sep = h < NH - 1;
    if (has_sep)
        *(float4*)(obase + NK * ND + d4) = *(const float4*)(sep + d4);

    if (lane < NK) {
        out_mask[(size_t)b * ROWS + h * (NK + 1) + lane] =
            (float)attn[(size_t)bh * NS + myi + 1];
        out_kid[(size_t)bh * NK + lane] = (float)myi;
    }
    if (lane == NK && has_sep)
        out_mask[(size_t)b * ROWS + h * (NK + 1) + NK] = 1.0f;
}

// ---------------------------------------------------------------------------
extern "C" void kernel_launch(void* const* d_in, const int* in_sizes, int n_in,
                              void* d_out, int out_size, void* d_ws, size_t ws_size,
                              hipStream_t stream) {
    const float* sel   = (const float*)d_in[0];
    const float* emb   = (const float*)d_in[1];
    const float* user  = (const float*)d_in[2];
    const float* nrp   = (const float*)d_in[3];
    const int*   attn  = (const int*)d_in[4];
    const int*   refin = (const int*)d_in[5];
    const float* W     = (const float*)d_in[6];
    const float* bal   = (const float*)d_in[7];
    const float* sep   = (const float*)d_in[8];
    const float* orde  = (const float*)d_in[9];

    float* qn  = (float*)d_ws;                       // NB*NH*ND floats (800 KB)
    float* scw = qn + (size_t)NB * NH * ND;          // NB*NH*NS floats (1.6 MB)

    float* out_terms = (float*)d_out;
    float* out_mask  = out_terms + (size_t)NB * ROWS * ND;
    float* out_kid   = out_mask + (size_t)NB * ROWS;

    query_kernel<<<NB * (NH / HB), 256, 0, stream>>>(user, nrp, W, bal, qn);
    score_kernel<<<NB * NH * CHUNKS, 256, 0, stream>>>(sel, qn, scw);
    topk_out_kernel<<<NB * NH, 64, 0, stream>>>(emb, attn, refin, scw, sep, orde,
                                                out_terms, out_mask, out_kid);
}